// Round 1
// baseline (790.609 us; speedup 1.0000x reference)
//
#include <hip/hip_runtime.h>
#include <stdint.h>

#define DIM   1024
#define WORDS 32      // 1024 bits / 32
#define NQ    512     // batch of queries
#define CAP   512     // bucket capacity per query (E[active]=36.8, P(>512)~0)
#define RPB   64      // address rows per block in k1

// ws layout:
//   [0,      2048)            int      cnt[512]
//   [2048,   2048+65536)      uint32_t qpacked[512][32]
//   [67584,  67584+512*512*4) uint32_t buckets[512][CAP]
// total: 1,116,160 B

// Pack 32 sign bits for one (row, lane) pair. Lane l owns dims {j*128 + 4l + e},
// bit position 4j+e. Permutation is arbitrary but MUST be identical for queries
// and addresses (it is: both call this). Loads are coalesced: per j, lanes 0..31
// cover a contiguous 512B segment of the row.
__device__ __forceinline__ uint32_t pack_word(const float* __restrict__ row, int lane) {
  uint32_t u = 0;
#pragma unroll
  for (int j = 0; j < 8; ++j) {
    const float4 v = *reinterpret_cast<const float4*>(row + j * 128 + lane * 4);
    const uint32_t b0 = __float_as_uint(v.x) >> 31;  // +1.0 -> 0, -1.0 -> 1
    const uint32_t b1 = __float_as_uint(v.y) >> 31;
    const uint32_t b2 = __float_as_uint(v.z) >> 31;
    const uint32_t b3 = __float_as_uint(v.w) >> 31;
    u |= (b0 << (4 * j)) | (b1 << (4 * j + 1)) | (b2 << (4 * j + 2)) | (b3 << (4 * j + 3));
  }
  return u;
}

// k0: pack the 512 query rows into ws, zero the per-query counters.
// grid 64 x 256: each wave packs 2 rows (lanes 0-31 row A, 32-63 row B).
__global__ __launch_bounds__(256) void k0_pack_queries(const float* __restrict__ address,
                                                       uint32_t* __restrict__ qpacked,
                                                       int* __restrict__ cnt) {
  const int t = threadIdx.x;
  const int gw = blockIdx.x * 4 + (t >> 6);   // global wave id 0..255
  const int row = gw * 2 + ((t >> 5) & 1);    // 0..511
  const int lane = t & 31;
  qpacked[row * WORDS + lane] = pack_word(address + (size_t)row * DIM, lane);
  const int gid = blockIdx.x * 256 + t;
  if (gid < NQ) cnt[gid] = 0;
}

// k1: stream 64 address rows per block, pack to bits in LDS, then each thread
// holds one packed row in 32 VGPRs and XOR-popcounts it against 128 queries.
// Query words are read with a wave-uniform index -> scalar s_load path (no LDS).
// sim >= thr  <=>  popc <= (1024 - thr)/2   (exact integer math).
__global__ __launch_bounds__(256) void k1_similarity(const float* __restrict__ addresses,
                                                     const uint32_t* __restrict__ qpacked,
                                                     const void* __restrict__ thr_raw,
                                                     int* __restrict__ cnt,
                                                     uint32_t* __restrict__ buckets,
                                                     int N) {
  __shared__ uint32_t rows_lds[RPB * 33];  // stride 33 breaks the 32-bank stride
  const int t = threadIdx.x;
  const int base = blockIdx.x * RPB;

  // Phase A: pack 64 rows (8 rows per iteration across 256 threads)
  {
    const int lane = t & 31;
    const int sub = t >> 5;  // 0..7
#pragma unroll
    for (int it = 0; it < 8; ++it) {
      const int lr = it * 8 + sub;
      const int n = base + lr;
      uint32_t u = 0;
      if (n < N) u = pack_word(addresses + (size_t)n * DIM, lane);
      rows_lds[lr * 33 + lane] = u;
    }
  }

  // Resolve threshold: harness may pass int32 110 or float32 110.0
  int thr;
  {
    const int ti = *reinterpret_cast<const int*>(thr_raw);
    if (ti >= -DIM && ti <= DIM) {
      thr = ti;
    } else {
      const float tf = *reinterpret_cast<const float*>(thr_raw);
      thr = (int)floorf(tf + 0.5f);
    }
  }
  const int limit = (DIM - thr) >> 1;  // active iff popc <= limit

  __syncthreads();

  // Phase B: one packed row per thread, in registers.
  const int rlane = t & 63;
  const int n = base + rlane;
  uint32_t rw[WORDS];
#pragma unroll
  for (int k = 0; k < WORDS; ++k) rw[k] = rows_lds[rlane * 33 + k];  // conflict-free (stride 33)

  if (n >= N) return;  // tail block only; no barriers after this point

  // Wave w handles queries [w*128, (w+1)*128). readfirstlane makes the index
  // provably wave-uniform so query loads become scalar loads.
  const int wv = __builtin_amdgcn_readfirstlane(t >> 6);
  const int b0 = wv * 128;
  for (int bb = 0; bb < 128; ++bb) {
    const int b = b0 + bb;
    const uint4* __restrict__ q4 = reinterpret_cast<const uint4*>(qpacked + (size_t)b * WORDS);
    int p0 = 0, p1 = 0, p2 = 0, p3 = 0;  // 4 chains to break bcnt dependence
#pragma unroll
    for (int k8 = 0; k8 < 8; ++k8) {
      const uint4 qv = q4[k8];
      p0 += __popc(rw[4 * k8 + 0] ^ qv.x);
      p1 += __popc(rw[4 * k8 + 1] ^ qv.y);
      p2 += __popc(rw[4 * k8 + 2] ^ qv.z);
      p3 += __popc(rw[4 * k8 + 3] ^ qv.w);
    }
    if (p0 + p1 + p2 + p3 <= limit) {
      const int idx = atomicAdd(&cnt[b], 1);  // device-scope, cross-XCD safe
      if (idx < CAP) buckets[(size_t)b * CAP + idx] = (uint32_t)n;
    }
  }
}

// k2: one block per query. Sum the ~37 active content rows (f64 accumulate to
// keep the sign exact), write sign. Every output element is written.
__global__ __launch_bounds__(256) void k2_gather(const float* __restrict__ content,
                                                 const int* __restrict__ cnt,
                                                 const uint32_t* __restrict__ buckets,
                                                 float* __restrict__ out) {
  __shared__ uint32_t list[CAP];
  const int b = blockIdx.x;
  const int t = threadIdx.x;
  int c = cnt[b];
  if (c > CAP) c = CAP;
  for (int i = t; i < c; i += 256) list[i] = buckets[(size_t)b * CAP + i];
  __syncthreads();

  double a0 = 0, a1 = 0, a2 = 0, a3 = 0;
  const float4* __restrict__ c4 = reinterpret_cast<const float4*>(content);
  for (int i = 0; i < c; ++i) {
    const float4 v = c4[(size_t)list[i] * (DIM / 4) + t];  // coalesced
    a0 += v.x; a1 += v.y; a2 += v.z; a3 += v.w;
  }
  float4 r;
  r.x = a0 > 0.0 ? 1.0f : (a0 < 0.0 ? -1.0f : 0.0f);
  r.y = a1 > 0.0 ? 1.0f : (a1 < 0.0 ? -1.0f : 0.0f);
  r.z = a2 > 0.0 ? 1.0f : (a2 < 0.0 ? -1.0f : 0.0f);
  r.w = a3 > 0.0 ? 1.0f : (a3 < 0.0 ? -1.0f : 0.0f);
  reinterpret_cast<float4*>(out)[(size_t)b * (DIM / 4) + t] = r;
}

extern "C" void kernel_launch(void* const* d_in, const int* in_sizes, int n_in,
                              void* d_out, int out_size, void* d_ws, size_t ws_size,
                              hipStream_t stream) {
  const float* address   = (const float*)d_in[0];
  const float* addresses = (const float*)d_in[1];
  const float* content   = (const float*)d_in[2];
  const void*  thr       = d_in[3];
  const int N = in_sizes[1] / DIM;  // 100000

  char* ws = (char*)d_ws;
  int*      cnt     = (int*)ws;                                   // 2 KB
  uint32_t* qpacked = (uint32_t*)(ws + 2048);                     // 64 KB
  uint32_t* buckets = (uint32_t*)(ws + 2048 + NQ * WORDS * 4);    // 1 MB

  k0_pack_queries<<<64, 256, 0, stream>>>(address, qpacked, cnt);
  const int nb = (N + RPB - 1) / RPB;
  k1_similarity<<<nb, 256, 0, stream>>>(addresses, qpacked, thr, cnt, buckets, N);
  k2_gather<<<NQ, 256, 0, stream>>>(content, cnt, buckets, (float*)d_out);
}